// Round 4
// baseline (308.775 us; speedup 1.0000x reference)
//
#include <hip/hip_runtime.h>

#define Bz 32
#define Nn 510
#define Dd 64
#define Hh 4
#define HD_ 256
#define Kpad 512
#define ALPHA_ 0.1f
#define LNEPS 1e-5f
#define SLOPE 0.01f
#define NEG_INF -3.0e38f

typedef __attribute__((ext_vector_type(8))) short short8;
typedef __attribute__((ext_vector_type(4))) float floatx4;

__device__ inline float wredsum(float v) {
  #pragma unroll
  for (int off = 32; off; off >>= 1) v += __shfl_xor(v, off, 64);
  return v;
}
__device__ inline float wredmax(float v) {
  #pragma unroll
  for (int off = 32; off; off >>= 1) v = fmaxf(v, __shfl_xor(v, off, 64));
  return v;
}
__device__ inline unsigned short f2bf(float f) {
  unsigned int u = __float_as_uint(f);
  unsigned int r = (u + 0x7fffu + ((u >> 16) & 1u)) >> 16;
  return (unsigned short)r;
}
__device__ inline float bf2f(unsigned short u) {
  return __uint_as_float(((unsigned int)u) << 16);
}

// K1: xt = x@W; writes xtT bf16 [b][h][d][m(512 padded)] and si/sj (fused).
__global__ __launch_bounds__(256) void k1_xt(const float* __restrict__ x,
                                             const float* __restrict__ W,
                                             const float* __restrict__ attw,
                                             unsigned short* __restrict__ xtT,
                                             float* __restrict__ si,
                                             float* __restrict__ sj) {
  __shared__ float Wl[64][132];
  __shared__ float xr[32][68];
  const int t = threadIdx.x;
  const int rt = blockIdx.x;
  const int b = blockIdx.y;
  const int ch = blockIdx.z;
  #pragma unroll
  for (int k = 0; k < 8; k++) {
    int f = t + k * 256;
    int kr = f >> 5;
    int c = (f & 31) * 4;
    float4 v = *(const float4*)&W[kr * HD_ + ch * 128 + c];
    *(float4*)&Wl[kr][c] = v;
  }
  #pragma unroll
  for (int k = 0; k < 2; k++) {
    int f = t + k * 256;
    int r = f >> 4;
    int c = (f & 15) * 4;
    int row = rt * 32 + r;
    float4 v = make_float4(0.f, 0.f, 0.f, 0.f);
    if (row < Nn) v = *(const float4*)&x[(b * Nn + row) * Dd + c];
    *(float4*)&xr[r][c] = v;
  }
  __syncthreads();
  const int tr = t >> 5, tc = t & 31;
  const int rb = tr * 4, c0 = tc * 4;
  float acc[4][4] = {};
  #pragma unroll
  for (int k4 = 0; k4 < 16; k4++) {
    float4 xv[4];
    #pragma unroll
    for (int r = 0; r < 4; r++) xv[r] = *(float4*)&xr[rb + r][k4 * 4];
    #pragma unroll
    for (int kk = 0; kk < 4; kk++) {
      float4 wv = *(float4*)&Wl[k4 * 4 + kk][c0];
      #pragma unroll
      for (int r = 0; r < 4; r++) {
        float xs = (&xv[r].x)[kk];
        acc[r][0] = fmaf(xs, wv.x, acc[r][0]);
        acc[r][1] = fmaf(xs, wv.y, acc[r][1]);
        acc[r][2] = fmaf(xs, wv.z, acc[r][2]);
        acc[r][3] = fmaf(xs, wv.w, acc[r][3]);
      }
    }
  }
  const int colbase = ch * 128 + c0;
  const int h = colbase >> 6;
  const int dd = colbase & 63;
  const int m0r = rt * 32 + rb;
  #pragma unroll
  for (int cc = 0; cc < 4; cc++) {
    unsigned short* p = &xtT[((size_t)(b * 4 + h) * 64 + (dd + cc)) * Kpad + m0r];
    if (m0r + 3 < Nn) {
      ushort4 u;
      u.x = f2bf(acc[0][cc]); u.y = f2bf(acc[1][cc]);
      u.z = f2bf(acc[2][cc]); u.w = f2bf(acc[3][cc]);
      *(ushort4*)p = u;
    } else {
      #pragma unroll
      for (int r = 0; r < 4; r++) if (m0r + r < Nn) p[r] = f2bf(acc[r][cc]);
    }
  }
  float w1v[4], w2v[4];
  #pragma unroll
  for (int cc = 0; cc < 4; cc++) {
    w1v[cc] = attw[h * 128 + dd + cc];
    w2v[cc] = attw[h * 128 + 64 + dd + cc];
  }
  #pragma unroll
  for (int r = 0; r < 4; r++) {
    float p1 = acc[r][0] * w1v[0] + acc[r][1] * w1v[1] +
               acc[r][2] * w1v[2] + acc[r][3] * w1v[3];
    float p2 = acc[r][0] * w2v[0] + acc[r][1] * w2v[1] +
               acc[r][2] * w2v[2] + acc[r][3] * w2v[3];
    #pragma unroll
    for (int off = 1; off <= 8; off <<= 1) {
      p1 += __shfl_xor(p1, off, 64);
      p2 += __shfl_xor(p2, off, 64);
    }
    if ((tc & 15) == 0) {
      int row = m0r + r;
      if (row < Nn) {
        si[(b * 4 + h) * Nn + row] = p1;
        sj[(b * 4 + h) * Nn + row] = p2;
      }
    }
  }
}

// K2a: cc[h][i][j] = 0.9*(conv3x3(causal)[i][j] + cb[h]); batch-independent.
__global__ __launch_bounds__(256) void k2a(const float* __restrict__ causal,
                                           const float* __restrict__ convw,
                                           const float* __restrict__ convb,
                                           float* __restrict__ cc) {
  __shared__ float clds[3][520];
  const int t = threadIdx.x;
  const int i = blockIdx.x;
  for (int f = t; f < 3 * 514; f += 256) {
    int r = f / 514, jj = f - r * 514;
    int iq = i - 1 + r, j = jj - 1;
    clds[r][jj] = (iq >= 0 && iq < Nn && j >= 0 && j < Nn) ? causal[iq * Nn + j] : 0.f;
  }
  __syncthreads();
  const int j0 = t * 2;
  #pragma unroll
  for (int h = 0; h < 4; h++) {
    float u[9];
    #pragma unroll
    for (int q = 0; q < 9; q++) u[q] = convw[h * 18 + 9 + q];
    float s0 = convb[h], s1 = convb[h];
    #pragma unroll
    for (int r3 = 0; r3 < 3; r3++) {
      #pragma unroll
      for (int dj = 0; dj < 3; dj++) {
        float wv = u[r3 * 3 + dj];
        s0 = fmaf(wv, clds[r3][j0 + dj], s0);
        s1 = fmaf(wv, clds[r3][j0 + 1 + dj], s1);
      }
    }
    float* o = &cc[((size_t)h * Nn + i) * 512 + j0];
    o[0] = 0.9f * s0;
    o[1] = 0.9f * s1;
  }
}

// K23: fused scores->softmax->A-write->A@xtT MFMA->fcg/GLU/LN.
// Grid (64 itiles of 8, 32 b), 256 thr = 4 waves.
__global__ __launch_bounds__(256) void k23(const float* __restrict__ si,
                                           const float* __restrict__ sj,
                                           const float* __restrict__ cc,
                                           const unsigned short* __restrict__ xtT,
                                           const float* __restrict__ convw,
                                           const float* __restrict__ x,
                                           const float* __restrict__ fcgw,
                                           const float* __restrict__ fcgb,
                                           const float* __restrict__ lng,
                                           const float* __restrict__ lnb,
                                           float* __restrict__ A,
                                           float* __restrict__ y) {
  __shared__ unsigned short am_t[10 * 8 * 66];  // [r][e=j&7][c=(j>>3)+1] bf16
  __shared__ unsigned short sjl[4 * 8 * 66];    // [h][e][c] bf16
  __shared__ unsigned short Al[9 * 520];        // A tile bf16 [row][k]; row8=zeros
  __shared__ float ol[8][64];
  __shared__ float gl[2][128];
  __shared__ float sil[4][10];
  const int t = threadIdx.x;
  const int i0 = blockIdx.x * 8;
  const int b = blockIdx.y;
  // one-time init: zero row 8 of Al
  if (t < 130) ((uint2*)&Al[8 * 520])[t] = make_uint2(0u, 0u);
  if (t < 40) {
    int h = t / 10, r = t - h * 10;
    int iq = i0 + r - 1;
    sil[h][r] = (iq >= 0 && iq < Nn) ? si[(b * 4 + h) * Nn + iq] : 0.f;
  }
  // am_t boundary zeros (c=0 and c=65)
  if (t >= 64 && t < 224) {
    int q = t - 64;
    int r = q >> 4, rem = q & 15;
    int e = rem >> 1, side = rem & 1;
    am_t[(r * 8 + e) * 66 + side * 65] = 0;
  }
  for (int f = t; f < 2048; f += 256) {
    int h = f >> 9, j = f & 511;
    float v = (j < Nn) ? sj[(b * 4 + h) * Nn + j] : 0.f;
    sjl[(h * 8 + (j & 7)) * 66 + (j >> 3) + 1] = f2bf(v);
  }
  __syncthreads();
  // am staging: rows r=0..9 (iq = i0+r-1), bf16 transposed
  for (int f = t; f < 5120; f += 256) {
    int r = f >> 9, j = f & 511;
    int iq = i0 + r - 1;
    float am = 0.f;
    if (iq >= 0 && iq < Nn && j < Nn) {
      float s = 0.f;
      #pragma unroll
      for (int h = 0; h < 4; h++) {
        float e2 = sil[h][r] + bf2f(sjl[(h * 8 + (j & 7)) * 66 + (j >> 3) + 1]);
        s += (e2 >= 0.f) ? e2 : SLOPE * e2;
      }
      am = 0.25f * s;
    }
    am_t[(r * 8 + (j & 7)) * 66 + (j >> 3) + 1] = f2bf(am);
  }
  __syncthreads();
  const int w = t >> 6, L = t & 63;
  const int quad = L >> 4, l16 = L & 15;
  const int j0 = L * 8;
  floatx4 acc = {0.f, 0.f, 0.f, 0.f};
  for (int h = 0; h < 4; h++) {
    float cw9[9];
    #pragma unroll
    for (int q = 0; q < 9; q++) cw9[q] = convw[h * 18 + q];
    #pragma unroll
    for (int rr = 0; rr < 2; rr++) {
      const int il = w * 2 + rr;
      const int i = i0 + il;
      if (i < Nn) {
        float conv[8];
        #pragma unroll
        for (int e = 0; e < 8; e++) conv[e] = 0.f;
        #pragma unroll
        for (int r3 = 0; r3 < 3; r3++) {
          const unsigned short* ba = &am_t[((il + r3) * 8) * 66];
          float a[10];
          a[0] = bf2f(ba[7 * 66 + L]);
          #pragma unroll
          for (int e = 0; e < 8; e++) a[1 + e] = bf2f(ba[e * 66 + L + 1]);
          a[9] = bf2f(ba[0 * 66 + L + 2]);
          float w0 = cw9[r3 * 3], w1 = cw9[r3 * 3 + 1], w2 = cw9[r3 * 3 + 2];
          #pragma unroll
          for (int e = 0; e < 8; e++)
            conv[e] = fmaf(w0, a[e], fmaf(w1, a[e + 1], fmaf(w2, a[e + 2], conv[e])));
        }
        float ccv[8];
        const float* ccp = &cc[((size_t)h * Nn + i) * 512 + j0];
        *(float4*)&ccv[0] = *(const float4*)&ccp[0];
        *(float4*)&ccv[4] = *(const float4*)&ccp[4];
        const float sih = sil[h][il + 1];
        float v[8];
        float mx = NEG_INF;
        #pragma unroll
        for (int e = 0; e < 8; e++) {
          float e2 = sih + bf2f(sjl[(h * 8 + e) * 66 + L + 1]);
          float l = (e2 >= 0.f) ? e2 : SLOPE * e2;
          float val = fmaf(0.9f, conv[e], fmaf(ALPHA_, l, ccv[e]));
          v[e] = (j0 + e < Nn) ? val : NEG_INF;
          mx = fmaxf(mx, v[e]);
        }
        mx = wredmax(mx);
        float p[8], s = 0.f;
        #pragma unroll
        for (int e = 0; e < 8; e++) {
          p[e] = __expf(v[e] - mx);
          s += p[e];
        }
        s = wredsum(s);
        const float inv = 1.f / s;
        #pragma unroll
        for (int e = 0; e < 8; e++) p[e] *= inv;
        float* Ar = &A[((size_t)(b * 4 + h) * Nn + i) * Nn + j0];
        *(float4*)&Ar[0] = make_float4(p[0], p[1], p[2], p[3]);
        if (L < 63) *(float4*)&Ar[4] = make_float4(p[4], p[5], p[6], p[7]);
        else        *(float2*)&Ar[4] = make_float2(p[4], p[5]);
        short8 ps;
        #pragma unroll
        for (int e = 0; e < 8; e++) ps[e] = (short)f2bf(p[e]);
        *(short8*)&Al[il * 520 + j0] = ps;
      }
    }
    __syncthreads();
    // MFMA: B-frag direct from global (L2-hot), A-frag from LDS.
    const unsigned short* Xb = xtT + ((size_t)(b * 4 + h) * 64 + (w * 16 + l16)) * Kpad;
    const unsigned short* Ap = &Al[(l16 < 8 ? l16 : 8) * 520 + quad * 8];
    #pragma unroll 4
    for (int ks = 0; ks < 16; ks++) {
      short8 af = *(const short8*)&Ap[ks * 32];
      short8 bf = *(const short8*)&Xb[ks * 32 + quad * 8];
      acc = __builtin_amdgcn_mfma_f32_16x16x32_bf16(af, bf, acc, 0, 0, 0);
    }
    __syncthreads();
  }
  #pragma unroll
  for (int reg = 0; reg < 4; reg++) {
    int row = quad * 4 + reg;
    if (row < 8) ol[row][w * 16 + l16] = 0.25f * acc[reg];
  }
  __syncthreads();
  const int kk = t & 127;
  const int rg = t >> 7;
  for (int it = 0; it < 4; it++) {
    const int r = it * 2 + rg;
    const int row = i0 + r;
    float g = fcgb[kk];
    #pragma unroll
    for (int d = 0; d < 64; d++) g = fmaf(ol[r][d], fcgw[d * 128 + kk], g);
    gl[rg][kk] = g;
    __syncthreads();
    if (kk < 64 && row < Nn) {
      float a = gl[rg][kk];
      float bb = gl[rg][kk + 64];
      float glu = a / (1.f + __expf(-bb));
      float yv = glu + x[(b * Nn + row) * Dd + kk];
      float mu = wredsum(yv) * (1.f / 64.f);
      float dv = yv - mu;
      float var = wredsum(dv * dv) * (1.f / 64.f);
      float o = dv * rsqrtf(var + LNEPS) * lng[kk] + lnb[kk];
      y[(b * Nn + row) * Dd + kk] = o;
    }
    __syncthreads();
  }
}

extern "C" void kernel_launch(void* const* d_in, const int* in_sizes, int n_in,
                              void* d_out, int out_size, void* d_ws, size_t ws_size,
                              hipStream_t stream) {
  const float* x      = (const float*)d_in[0];
  const float* causal = (const float*)d_in[1];
  const float* W      = (const float*)d_in[2];
  const float* attw   = (const float*)d_in[3];
  const float* convw  = (const float*)d_in[4];
  const float* convb  = (const float*)d_in[5];
  const float* fcgw   = (const float*)d_in[6];
  const float* fcgb   = (const float*)d_in[7];
  const float* lng    = (const float*)d_in[8];
  const float* lnb    = (const float*)d_in[9];

  float* ws = (float*)d_ws;
  float* si = ws;                                  // 65,280 floats
  float* sj = si + (size_t)Bz * Hh * Nn;           // 65,280 floats (+16 pad)
  unsigned short* xtT = (unsigned short*)(sj + (size_t)Bz * Hh * Nn + 16);
  size_t xtT_elems = (size_t)Bz * Hh * Dd * Kpad;  // 4,194,304 shorts = 8.4 MB
  float* cc = (float*)(xtT + xtT_elems);           // 4*510*512 floats = 4.2 MB

  float* yout = (float*)d_out;                     // 32*510*64
  float* Aout = yout + (size_t)Bz * Nn * Dd;       // 32*4*510*510

  hipMemsetAsync(xtT, 0, xtT_elems * sizeof(unsigned short), stream);
  k1_xt<<<dim3(16, Bz, 2), 256, 0, stream>>>(x, W, attw, xtT, si, sj);
  k2a  <<<Nn, 256, 0, stream>>>(causal, convw, convb, cc);
  k23  <<<dim3(64, Bz), 256, 0, stream>>>(si, sj, cc, xtT, convw, x,
                                          fcgw, fcgb, lng, lnb, Aout, yout);
}